// Round 4
// baseline (142.674 us; speedup 1.0000x reference)
//
#include <hip/hip_runtime.h>
#include <hip/hip_bf16.h>
#include <math.h>

// NT-Xent loss, fused flash-style. N=8192 rows, D=256. Two kernels:
//   k_norm: row L2-normalize fp32 -> bf16 (ws); exact fp32 pos[i] =
//           cos(f_i, f_{i+N/2}); zero sumexp/counter/out
//   k_sim : bf16 MFMA sim tiles, exp((sim-1)/T) in-register, per-row sum
//           atomics; LAST block (atomic counter) computes mean NLL -> out
//
// Register-budget history:
//   R1 64x64 @(256,2): ~280 demand > 256 -> 24 MB spill writes, 77 us
//   R2 32x64 @(256,3): 168 budget < ~230 -> 125 MB spill writes, 82 us
//   R3 32x64 @(256,2): no spill, 49.5 us; LDS-bound (~20 us ds_read: every
//      wave ingests the whole B tile -> 4x duplication)
//   R4 64x32 @(256,2): waves split cols, share A rows -> B tile read once
//      per block (LDS ~10 us), afrag 128 VGPR, est total ~224 < 256
#define N_ROWS 8192
#define D_DIM  256
#define HALF_N 4096
#define INV_T      14.285714285714286f      // 1/0.07
#define SCALE_LOG2 20.609929155556620f      // log2(e)/0.07
#define NEG_SCALE  -20.609929155556620f
#define EPSV   1e-8f
#define GRID_SIM 512

typedef __attribute__((ext_vector_type(8))) short bf16x8;   // 8 bf16 = 4 VGPR
typedef __attribute__((ext_vector_type(4))) float f32x4;

#define AS1 __attribute__((address_space(1)))
#define AS3 __attribute__((address_space(3)))

__device__ inline unsigned short f2bf(float x) {
    unsigned int u = __float_as_uint(x);
    unsigned int r = (u + 0x7fffu + ((u >> 16) & 1u)) >> 16;   // RNE
    return (unsigned short)r;
}

// ---------------- kernel 1: normalize + exact pos + zero accumulators ------
__global__ __launch_bounds__(256) void k_norm(const float* __restrict__ feat,
                                              unsigned short* __restrict__ fbf,
                                              float* __restrict__ sumexp,
                                              float* __restrict__ pos,
                                              unsigned int* __restrict__ counter,
                                              float* __restrict__ out) {
    const int tid = threadIdx.x;
    const int gid = blockIdx.x * 256 + tid;
    if (gid < N_ROWS) sumexp[gid] = 0.f;
    if (gid == 0) { out[0] = 0.f; *counter = 0u; }

    const int w = tid >> 6, lane = tid & 63;
    const int row = blockIdx.x * 4 + w;              // 2048 blocks * 4 rows
    const int pc  = (row + HALF_N) & (N_ROWS - 1);
    const float4 v = ((const float4*)(feat + row * D_DIM))[lane];
    const float4 p = ((const float4*)(feat + pc  * D_DIM))[lane];
    float ss  = v.x*v.x + v.y*v.y + v.z*v.z + v.w*v.w;
    float sp  = p.x*p.x + p.y*p.y + p.z*p.z + p.w*p.w;
    float dot = v.x*p.x + v.y*p.y + v.z*p.z + v.w*p.w;
    #pragma unroll
    for (int off = 32; off; off >>= 1) {
        ss  += __shfl_xor(ss,  off);
        sp  += __shfl_xor(sp,  off);
        dot += __shfl_xor(dot, off);
    }
    const float scale = 1.f / fmaxf(sqrtf(ss), EPSV);
    ushort4 o;
    o.x = f2bf(v.x * scale);
    o.y = f2bf(v.y * scale);
    o.z = f2bf(v.z * scale);
    o.w = f2bf(v.w * scale);
    ((ushort4*)(fbf + row * D_DIM))[lane] = o;
    if (lane == 0)
        pos[row] = dot / (fmaxf(sqrtf(ss), EPSV) * fmaxf(sqrtf(sp), EPSV));
}

// ---------------- kernel 2: fused sim + exp + row-sum + finalize -----------
// grid = 512: rt = blockIdx>>2 (128 row tiles of 64), cs = blockIdx&3
// (2048-col slice; cs == blockIdx&3 keeps each XCD's B slice L2-resident).
// 4 waves split the 128-col B tile: wave w owns cols [w*32, w*32+32) for all
// 64 rows -> B tile ds_read exactly once per block. A (64 rows x 256 k) in
// regs (identical across waves): 32 frags = 128 VGPR. B tile 128x256 = 64 KB
// LDS via global_load_lds w=16, XOR-16B-chunk swizzle (conflict-free b128).
__global__ __launch_bounds__(256, 2) void k_sim(const unsigned short* __restrict__ fbf,
                                                float* __restrict__ sumexp,
                                                const float* __restrict__ pos,
                                                unsigned int* __restrict__ counter,
                                                float* __restrict__ out) {
    __shared__ __align__(16) char Bs[65536];
    __shared__ float redbuf[4];
    __shared__ int isLast;
    const int tid  = threadIdx.x;
    const int lane = tid & 63;
    const int w    = tid >> 6;
    const int q    = lane >> 4, l15 = lane & 15;
    const int rt = blockIdx.x >> 2, cs = blockIdx.x & 3;
    const int rowBase = rt * 64;
    const int csBase  = cs * 2048;

    // --- issue DMA for jt=0 while afrag loads are in flight ---
    {
        const char* Bg = (const char*)fbf + (size_t)csBase * 512;
        #pragma unroll
        for (int i = 0; i < 16; ++i) {             // 16 x 4 KB = 64 KB
            const int idx = i * 256 + tid;         // 16B chunk 0..4095
            const int col = idx >> 5;              // local col 0..127
            const int cir = idx & 31;
            __builtin_amdgcn_global_load_lds(
                (const AS1 void*)(Bg + col * 512 + ((cir ^ (col & 7)) << 4)),
                (AS3 void*)(Bs + idx * 16), 16, 0, 0);
        }
    }

    // A fragments: rows rowBase + ri*16 + l15, k = t*32 + q*8 + j
    bf16x8 afrag[8][4];
    #pragma unroll
    for (int t = 0; t < 8; ++t)
        #pragma unroll
        for (int ri = 0; ri < 4; ++ri)
            afrag[t][ri] = *(const bf16x8*)(fbf + (rowBase + ri*16 + l15) * D_DIM
                                                + t*32 + q*8);

    float rsum[4][4];
    #pragma unroll
    for (int ri = 0; ri < 4; ++ri)
        #pragma unroll
        for (int r = 0; r < 4; ++r) rsum[ri][r] = 0.f;

    #pragma unroll 1                               // keep DMA live ranges tight
    for (int jt = 0; jt < 16; ++jt) {
        const int colBase = csBase + jt * 128;

        __syncthreads();                           // DMA of tile jt drained

        f32x4 acc[4][2];
        #pragma unroll
        for (int ri = 0; ri < 4; ++ri)
            #pragma unroll
            for (int ci = 0; ci < 2; ++ci) acc[ri][ci] = (f32x4){0.f, 0.f, 0.f, 0.f};

        #pragma unroll
        for (int t = 0; t < 8; ++t) {
            bf16x8 bfrag[2];
            #pragma unroll
            for (int ci = 0; ci < 2; ++ci) {
                const int c   = w * 32 + ci * 16 + l15;   // local col 0..127
                const int cir = t * 4 + q;                // k-chunk
                bfrag[ci] = *(const bf16x8*)(Bs + c * 512 + ((cir ^ (c & 7)) << 4));
            }
            #pragma unroll
            for (int ri = 0; ri < 4; ++ri)
                #pragma unroll
                for (int ci = 0; ci < 2; ++ci)
                    acc[ri][ci] = __builtin_amdgcn_mfma_f32_16x16x32_bf16(
                        afrag[t][ri], bfrag[ci], acc[ri][ci], 0, 0, 0);
        }

        // B tile consumed; start DMA for jt+1 so it overlaps the exp epilogue
        if (jt < 15) {
            __syncthreads();                       // all waves done reading Bs
            const char* Bg = (const char*)fbf + (size_t)(colBase + 128) * 512;
            #pragma unroll
            for (int i = 0; i < 16; ++i) {
                const int idx = i * 256 + tid;
                const int col = idx >> 5;
                const int cir = idx & 31;
                __builtin_amdgcn_global_load_lds(
                    (const AS1 void*)(Bg + col * 512 + ((cir ^ (col & 7)) << 4)),
                    (AS3 void*)(Bs + idx * 16), 16, 0, 0);
            }
        }

        // epilogue: e = exp2(acc*S - S); diagonal zeroed; per-row accumulate.
        // C/D layout: col=l15, row=q*4+reg. Diagonal test is per-16x16-tile
        // wave-uniform -> branch, not per-element cndmask.
        #pragma unroll
        for (int ri = 0; ri < 4; ++ri) {
            const int trow = rowBase + ri * 16;
            #pragma unroll
            for (int ci = 0; ci < 2; ++ci) {
                const int tcol = colBase + w * 32 + ci * 16;
                if (trow == tcol) {                // diagonal tile (rare)
                    #pragma unroll
                    for (int r = 0; r < 4; ++r) {
                        const float e = __builtin_amdgcn_exp2f(
                            __builtin_fmaf(acc[ri][ci][r], SCALE_LOG2, NEG_SCALE));
                        rsum[ri][r] += (q * 4 + r == l15) ? 0.f : e;
                    }
                } else {
                    #pragma unroll
                    for (int r = 0; r < 4; ++r)
                        rsum[ri][r] += __builtin_amdgcn_exp2f(
                            __builtin_fmaf(acc[ri][ci][r], SCALE_LOG2, NEG_SCALE));
                }
            }
        }
    }

    // reduce across the 16 lanes of each quad (cols), then atomics (1/row/wave)
    #pragma unroll
    for (int ri = 0; ri < 4; ++ri)
        #pragma unroll
        for (int r = 0; r < 4; ++r) {
            float s = rsum[ri][r];
            s += __shfl_xor(s, 1);
            s += __shfl_xor(s, 2);
            s += __shfl_xor(s, 4);
            s += __shfl_xor(s, 8);
            if (l15 == 0)
                atomicAdd(&sumexp[rowBase + ri * 16 + q * 4 + r], s);
        }

    // -------- last block computes mean NLL (device-scope handoff) ---------
    __threadfence();
    if (tid == 0) {
        unsigned int prev = __hip_atomic_fetch_add(counter, 1u, __ATOMIC_ACQ_REL,
                                                   __HIP_MEMORY_SCOPE_AGENT);
        isLast = (prev == GRID_SIM - 1);
    }
    __syncthreads();
    if (isLast) {
        float accn = 0.f;
        for (int i = tid; i < N_ROWS; i += 256) {
            const float se = __hip_atomic_load(&sumexp[i], __ATOMIC_RELAXED,
                                               __HIP_MEMORY_SCOPE_AGENT);
            accn += logf(se) - pos[i] * INV_T;
        }
        #pragma unroll
        for (int off = 32; off; off >>= 1) accn += __shfl_xor(accn, off);
        if (lane == 0) redbuf[w] = accn;
        __syncthreads();
        if (tid == 0)
            out[0] = INV_T + (redbuf[0] + redbuf[1] + redbuf[2] + redbuf[3])
                             * (1.f / N_ROWS);
    }
}

extern "C" void kernel_launch(void* const* d_in, const int* in_sizes, int n_in,
                              void* d_out, int out_size, void* d_ws, size_t ws_size,
                              hipStream_t stream) {
    const float* feat = (const float*)d_in[0];
    char* ws = (char*)d_ws;
    unsigned short* fbf = (unsigned short*)ws;                       // 4 MB bf16
    float* sumexp = (float*)(ws + 4u*1024u*1024u);                   // 32 KB
    float* pos    = (float*)(ws + 4u*1024u*1024u + 32u*1024u);       // 32 KB
    unsigned int* counter = (unsigned int*)(ws + 4u*1024u*1024u + 64u*1024u);

    k_norm<<<N_ROWS / 4, 256, 0, stream>>>(feat, fbf, sumexp, pos, counter,
                                           (float*)d_out);
    k_sim <<<GRID_SIM,   256, 0, stream>>>(fbf, sumexp, pos, counter,
                                           (float*)d_out);
}

// Round 6
// 141.778 us; speedup vs baseline: 1.0063x; 1.0063x over previous
//
#include <hip/hip_runtime.h>
#include <hip/hip_bf16.h>
#include <math.h>

// NT-Xent loss, N=8192, D=256. Two regular kernels (R5's cooperative launch
// silently failed -> reverted to separate launches; R4's last-block finalize
// pattern is proven correct).
//   k_norm: normalize fp32->bf16 (ws), exact fp32 pos[i], zero accum/counter
//   k_sim : bf16 MFMA sim, exp((sim-1)/T), per-row sum atomics; last block
//           (atomic counter) computes mean NLL -> out.
//           128row x 1024col per block (grid 512, 2 blocks/CU);
//           waves 2x2: afrag 64 rows = 128 VGPR, 2x LDS read dup;
//           32-col B tiles (16 KB), 2x16KB single-barrier double-buffer:
//           barrier(jt) drains DMA(jt) which had the FULL jt-1 compute
//           window in flight; DMA(jt+1) issued right after the barrier.
// History: R1 64x64 spill 77us | R2 (256,3) 168-total-budget spill 82us |
//   R3 32x64 no-spill 49.5us (LDS 4x dup ~20us) | R4 64KB tiles 2-barrier
//   drain + 66KB LDS -> 88us, occ 16.5% | R5 coop launch no-op.
#define N_ROWS 8192
#define D_DIM  256
#define HALF_N 4096
#define INV_T      14.285714285714286f      // 1/0.07
#define SCALE_LOG2 20.609929155556620f      // log2(e)/0.07
#define NEG_SCALE  -20.609929155556620f
#define EPSV   1e-8f
#define GRID_SIM 512

typedef __attribute__((ext_vector_type(8))) short bf16x8;   // 8 bf16 = 4 VGPR
typedef __attribute__((ext_vector_type(4))) float f32x4;

#define AS1 __attribute__((address_space(1)))
#define AS3 __attribute__((address_space(3)))

__device__ inline unsigned short f2bf(float x) {
    unsigned int u = __float_as_uint(x);
    unsigned int r = (u + 0x7fffu + ((u >> 16) & 1u)) >> 16;   // RNE
    return (unsigned short)r;
}

// stage one 32col x 256k (16 KB) B tile: 4 x 16B chunks per thread,
// XOR-16B-chunk swizzle (conflict-free ds_read_b128 on the consume side;
// LDS dst is wave-uniform-base + lane*16 as global_load_lds requires)
__device__ inline void stage_tile(char* buf, const unsigned short* fbf,
                                  int colBase, int tid) {
    const char* Bg = (const char*)fbf + (size_t)colBase * 512;
    #pragma unroll
    for (int i = 0; i < 4; ++i) {
        const int idx = i * 256 + tid;       // 16B chunk 0..1023
        const int col = idx >> 5;            // local col 0..31
        const int cir = idx & 31;
        __builtin_amdgcn_global_load_lds(
            (const AS1 void*)(Bg + col * 512 + ((cir ^ (col & 7)) << 4)),
            (AS3 void*)(buf + idx * 16), 16, 0, 0);
    }
}

// ---------------- kernel 1: normalize + exact pos + zero accumulators ------
__global__ __launch_bounds__(256) void k_norm(const float* __restrict__ feat,
                                              unsigned short* __restrict__ fbf,
                                              float* __restrict__ sumexp,
                                              float* __restrict__ pos,
                                              unsigned int* __restrict__ counter,
                                              float* __restrict__ out) {
    const int tid = threadIdx.x;
    const int gid = blockIdx.x * 256 + tid;
    if (gid < N_ROWS) sumexp[gid] = 0.f;
    if (gid == 0) { out[0] = 0.f; *counter = 0u; }

    const int w = tid >> 6, lane = tid & 63;
    const int row = blockIdx.x * 4 + w;              // 2048 blocks * 4 rows
    const int pc  = (row + HALF_N) & (N_ROWS - 1);
    const float4 v = ((const float4*)(feat + row * D_DIM))[lane];
    const float4 p = ((const float4*)(feat + pc  * D_DIM))[lane];
    float ss  = v.x*v.x + v.y*v.y + v.z*v.z + v.w*v.w;
    float sp  = p.x*p.x + p.y*p.y + p.z*p.z + p.w*p.w;
    float dot = v.x*p.x + v.y*p.y + v.z*p.z + v.w*p.w;
    #pragma unroll
    for (int off = 32; off; off >>= 1) {
        ss  += __shfl_xor(ss,  off);
        sp  += __shfl_xor(sp,  off);
        dot += __shfl_xor(dot, off);
    }
    const float scale = 1.f / fmaxf(sqrtf(ss), EPSV);
    ushort4 o;
    o.x = f2bf(v.x * scale);
    o.y = f2bf(v.y * scale);
    o.z = f2bf(v.z * scale);
    o.w = f2bf(v.w * scale);
    ((ushort4*)(fbf + row * D_DIM))[lane] = o;
    if (lane == 0)
        pos[row] = dot / (fmaxf(sqrtf(ss), EPSV) * fmaxf(sqrtf(sp), EPSV));
}

// ---------------- kernel 2: fused sim + exp + row-sum + finalize -----------
// grid = 512: rt = bid>>3 (64 row tiles of 128), cs = bid&7 (1024-col slice;
// blockIdx%8 keeps each XCD's 0.5 MB B slice L2-resident).
__global__ __launch_bounds__(256, 2) void k_sim(const unsigned short* __restrict__ fbf,
                                                float* __restrict__ sumexp,
                                                const float* __restrict__ pos,
                                                unsigned int* __restrict__ counter,
                                                float* __restrict__ out) {
    __shared__ __align__(16) char Bs[32768];           // 2 x 16 KB dbuf
    __shared__ float redbuf[4];
    __shared__ int isLast;
    const int tid  = threadIdx.x;
    const int lane = tid & 63;
    const int w    = tid >> 6;
    const int q    = lane >> 4, l15 = lane & 15;
    const int bid  = blockIdx.x;
    const int rt = bid >> 3, cs = bid & 7;
    const int rg = w >> 1, cgrp = w & 1;               // 2x2 wave grid
    const int rowBase = rt * 128 + rg * 64;
    const int csBase  = cs * 1024;

    stage_tile(Bs, fbf, csBase, tid);                  // tile 0 -> buf 0

    // A fragments: rows rowBase + ri*16 + l15, k = t*32 + q*8 + j (128 VGPR)
    bf16x8 afrag[8][4];
    #pragma unroll
    for (int t = 0; t < 8; ++t)
        #pragma unroll
        for (int ri = 0; ri < 4; ++ri)
            afrag[t][ri] = *(const bf16x8*)(fbf + (rowBase + ri*16 + l15) * D_DIM
                                                + t*32 + q*8);

    float rsum[4][4];
    #pragma unroll
    for (int ri = 0; ri < 4; ++ri)
        #pragma unroll
        for (int r = 0; r < 4; ++r) rsum[ri][r] = 0.f;

    #pragma unroll 1
    for (int jt = 0; jt < 32; ++jt) {
        const int colBase = csBase + jt * 32;
        const char* bufc = Bs + ((jt & 1) << 14);

        __syncthreads();                   // tile jt landed (vmcnt drain had
                                           // the whole jt-1 compute window)
        if (jt < 31)                       // DMA jt+1 -> other buffer
            stage_tile(Bs + (((jt + 1) & 1) << 14), fbf, colBase + 32, tid);

        f32x4 acc[4];
        #pragma unroll
        for (int ri = 0; ri < 4; ++ri) acc[ri] = (f32x4){0.f, 0.f, 0.f, 0.f};

        #pragma unroll
        for (int t = 0; t < 8; ++t) {
            const int c   = cgrp * 16 + l15;           // local col 0..31
            const int cir = t * 4 + q;                 // k-chunk
            const bf16x8 bfrag =
                *(const bf16x8*)(bufc + c * 512 + ((cir ^ (c & 7)) << 4));
            #pragma unroll
            for (int ri = 0; ri < 4; ++ri)
                acc[ri] = __builtin_amdgcn_mfma_f32_16x16x32_bf16(
                    afrag[t][ri], bfrag, acc[ri], 0, 0, 0);
        }

        // epilogue: e = exp2(acc*S - S); diagonal zeroed; per-row accumulate.
        // C/D layout: col=l15, row=q*4+reg. Diagonal test per-16x16-tile.
        const int tcol = colBase + cgrp * 16;
        #pragma unroll
        for (int ri = 0; ri < 4; ++ri) {
            const int trow = rowBase + ri * 16;
            if (trow == tcol) {
                #pragma unroll
                for (int r = 0; r < 4; ++r) {
                    const float e = __builtin_amdgcn_exp2f(
                        __builtin_fmaf(acc[ri][r], SCALE_LOG2, NEG_SCALE));
                    rsum[ri][r] += (q * 4 + r == l15) ? 0.f : e;
                }
            } else {
                #pragma unroll
                for (int r = 0; r < 4; ++r)
                    rsum[ri][r] += __builtin_amdgcn_exp2f(
                        __builtin_fmaf(acc[ri][r], SCALE_LOG2, NEG_SCALE));
            }
        }
    }

    // quad-reduce (cols) then one atomic per row per wave
    #pragma unroll
    for (int ri = 0; ri < 4; ++ri)
        #pragma unroll
        for (int r = 0; r < 4; ++r) {
            float s = rsum[ri][r];
            s += __shfl_xor(s, 1);
            s += __shfl_xor(s, 2);
            s += __shfl_xor(s, 4);
            s += __shfl_xor(s, 8);
            if (l15 == 0)
                atomicAdd(&sumexp[rowBase + ri * 16 + q * 4 + r], s);
        }

    // -------- last block computes mean NLL (device-scope handoff) ---------
    __threadfence();
    if (tid == 0) {
        unsigned int prev = __hip_atomic_fetch_add(counter, 1u, __ATOMIC_ACQ_REL,
                                                   __HIP_MEMORY_SCOPE_AGENT);
        isLast = (prev == GRID_SIM - 1);
    }
    __syncthreads();
    if (isLast) {
        float accn = 0.f;
        for (int i = tid; i < N_ROWS; i += 256) {
            const float se = __hip_atomic_load(&sumexp[i], __ATOMIC_RELAXED,
                                               __HIP_MEMORY_SCOPE_AGENT);
            accn += logf(se) - pos[i] * INV_T;
        }
        #pragma unroll
        for (int off = 32; off; off >>= 1) accn += __shfl_xor(accn, off);
        if (lane == 0) redbuf[w] = accn;
        __syncthreads();
        if (tid == 0)
            out[0] = INV_T + (redbuf[0] + redbuf[1] + redbuf[2] + redbuf[3])
                             * (1.f / N_ROWS);
    }
}

extern "C" void kernel_launch(void* const* d_in, const int* in_sizes, int n_in,
                              void* d_out, int out_size, void* d_ws, size_t ws_size,
                              hipStream_t stream) {
    const float* feat = (const float*)d_in[0];
    char* ws = (char*)d_ws;
    unsigned short* fbf = (unsigned short*)ws;                       // 4 MB bf16
    float* sumexp = (float*)(ws + 4u*1024u*1024u);                   // 32 KB
    float* pos    = (float*)(ws + 4u*1024u*1024u + 32u*1024u);       // 32 KB
    unsigned int* counter = (unsigned int*)(ws + 4u*1024u*1024u + 64u*1024u);

    k_norm<<<N_ROWS / 4, 256, 0, stream>>>(feat, fbf, sumexp, pos, counter,
                                           (float*)d_out);
    k_sim <<<GRID_SIM,   256, 0, stream>>>(fbf, sumexp, pos, counter,
                                           (float*)d_out);
}

// Round 7
// 139.406 us; speedup vs baseline: 1.0234x; 1.0170x over previous
//
#include <hip/hip_runtime.h>
#include <hip/hip_bf16.h>
#include <math.h>

// NT-Xent loss, N=8192, D=256. Two kernels, k_sim is BARRIER-FREE + LDS-FREE:
// B fragments have the same lane layout as A fragments (lane l15 <-> col,
// k = q*8+j), so each wave loads B fragments DIRECTLY from global (L2-resident
// per-XCD slice) -- no staging, no __syncthreads, no lockstep.
//   k_norm: normalize fp32 -> bf16 in FRAGMENT-TILED layout (16-row blocks x
//           16B k-chunks: byte = (row>>4)*8192 + (k>>3)*256 + (row&15)*16
//           + (k&7)*2), exact fp32 pos[i], zero sumexp/counter/out.
//   k_sim : per-wave 64row x 512col tile; per 16-col step: 8 coalesced
//           global_load_dwordx4 (1 KB contiguous each) + 32 MFMA + exp
//           epilogue; per-row sum atomics; last block finalizes mean NLL.
// History: R1 64x64 spill 77us | R2 168-total-budget spill 82us | R3 32x64
//   no-spill 49.5us (LDS 4x dup) | R4 66KB LDS + 64KB DMA drains 88us |
//   R5 coop launch no-op | R6 16KB dbuf single-barrier 91us: per-jt period
//   6840 cyc vs ~500 issue -> the barrier/DMA lockstep IS the cost; removed.
#define N_ROWS 8192
#define D_DIM  256
#define HALF_N 4096
#define INV_T      14.285714285714286f      // 1/0.07
#define SCALE_LOG2 20.609929155556620f      // log2(e)/0.07
#define NEG_SCALE  -20.609929155556620f
#define EPSV   1e-8f
#define GRID_SIM 512

typedef __attribute__((ext_vector_type(8))) short bf16x8;   // 8 bf16 = 4 VGPR
typedef __attribute__((ext_vector_type(4))) float f32x4;

__device__ inline unsigned short f2bf(float x) {
    unsigned int u = __float_as_uint(x);
    unsigned int r = (u + 0x7fffu + ((u >> 16) & 1u)) >> 16;   // RNE
    return (unsigned short)r;
}

// ---------------- kernel 1: normalize + exact pos + zero accumulators ------
__global__ __launch_bounds__(256) void k_norm(const float* __restrict__ feat,
                                              char* __restrict__ fbf,
                                              float* __restrict__ sumexp,
                                              float* __restrict__ pos,
                                              unsigned int* __restrict__ counter,
                                              float* __restrict__ out) {
    const int tid = threadIdx.x;
    const int gid = blockIdx.x * 256 + tid;
    if (gid < N_ROWS) sumexp[gid] = 0.f;
    if (gid == 0) { out[0] = 0.f; *counter = 0u; }

    const int w = tid >> 6, lane = tid & 63;
    const int row = blockIdx.x * 4 + w;              // 2048 blocks * 4 rows
    const int pc  = (row + HALF_N) & (N_ROWS - 1);
    const float4 v = ((const float4*)(feat + row * D_DIM))[lane];
    const float4 p = ((const float4*)(feat + pc  * D_DIM))[lane];
    float ss  = v.x*v.x + v.y*v.y + v.z*v.z + v.w*v.w;
    float sp  = p.x*p.x + p.y*p.y + p.z*p.z + p.w*p.w;
    float dot = v.x*p.x + v.y*p.y + v.z*p.z + v.w*p.w;
    #pragma unroll
    for (int off = 32; off; off >>= 1) {
        ss  += __shfl_xor(ss,  off);
        sp  += __shfl_xor(sp,  off);
        dot += __shfl_xor(dot, off);
    }
    const float scale = 1.f / fmaxf(sqrtf(ss), EPSV);
    ushort4 o;
    o.x = f2bf(v.x * scale);
    o.y = f2bf(v.y * scale);
    o.z = f2bf(v.z * scale);
    o.w = f2bf(v.w * scale);
    // fragment-tiled store: this lane covers k = lane*4 .. lane*4+3
    // -> chunk kc = lane>>1, byte-in-chunk = (lane&1)*8
    *(ushort4*)(fbf + (size_t)(row >> 4) * 8192 + (lane >> 1) * 256
                    + (row & 15) * 16 + (lane & 1) * 8) = o;
    if (lane == 0)
        pos[row] = dot / (fmaxf(sqrtf(ss), EPSV) * fmaxf(sqrtf(sp), EPSV));
}

// ---------------- kernel 2: barrier-free fused sim + exp + row-sum ---------
// grid = 512: rt = bid>>3 (64 row-blocks of 128), cs = bid&7 (1024-col slice;
// bid%8 pins each XCD to one 512 KB L2-resident B slice). 4 waves: rg=w>>1
// picks 64-row half, ch=w&1 picks 512-col half. Wave tile 64 x 512.
__global__ __launch_bounds__(256, 2) void k_sim(const char* __restrict__ fbf,
                                                float* __restrict__ sumexp,
                                                const float* __restrict__ pos,
                                                unsigned int* __restrict__ counter,
                                                float* __restrict__ out) {
    __shared__ float redbuf[4];
    __shared__ int isLast;
    const int tid  = threadIdx.x;
    const int lane = tid & 63;
    const int w    = tid >> 6;
    const int q    = lane >> 4, l15 = lane & 15;
    const int bid  = blockIdx.x;
    const int rt = bid >> 3, cs = bid & 7;
    const int rowBase  = rt * 128 + (w >> 1) * 64;
    const int colBase0 = cs * 1024 + (w & 1) * 512;

    const size_t laneOff = (size_t)q * 256 + (size_t)l15 * 16;

    // A fragments: rows rowBase + ri*16 + l15, k = t*32 + q*8 + j (128 VGPR)
    // tiled layout -> each load is wave-contiguous 1 KB, imm offset t*1024
    bf16x8 afrag[8][4];
    #pragma unroll
    for (int ri = 0; ri < 4; ++ri) {
        const char* ap = fbf + (size_t)(rowBase / 16 + ri) * 8192 + laneOff;
        #pragma unroll
        for (int t = 0; t < 8; ++t)
            afrag[t][ri] = *(const bf16x8*)(ap + t * 1024);
    }

    float rsum[4][4];
    #pragma unroll
    for (int ri = 0; ri < 4; ++ri)
        #pragma unroll
        for (int r = 0; r < 4; ++r) rsum[ri][r] = 0.f;

    const char* bp = fbf + (size_t)(colBase0 / 16) * 8192 + laneOff;

    #pragma unroll 1
    for (int jt = 0; jt < 32; ++jt) {
        // 8 independent coalesced loads: cols colBase0+jt*16 + l15, all k
        bf16x8 bfrag[8];
        #pragma unroll
        for (int t = 0; t < 8; ++t)
            bfrag[t] = *(const bf16x8*)(bp + (size_t)jt * 8192 + t * 1024);

        f32x4 acc[4];
        #pragma unroll
        for (int ri = 0; ri < 4; ++ri) acc[ri] = (f32x4){0.f, 0.f, 0.f, 0.f};

        #pragma unroll
        for (int t = 0; t < 8; ++t)
            #pragma unroll
            for (int ri = 0; ri < 4; ++ri)
                acc[ri] = __builtin_amdgcn_mfma_f32_16x16x32_bf16(
                    afrag[t][ri], bfrag[t], acc[ri], 0, 0, 0);

        // epilogue: e = exp2(acc*S - S); diagonal zeroed; per-row accumulate.
        // C/D layout: col=l15, row=q*4+reg. Diagonal test per-16x16-tile.
        const int tcol = colBase0 + jt * 16;
        #pragma unroll
        for (int ri = 0; ri < 4; ++ri) {
            const int trow = rowBase + ri * 16;
            if (trow == tcol) {
                #pragma unroll
                for (int r = 0; r < 4; ++r) {
                    const float e = __builtin_amdgcn_exp2f(
                        __builtin_fmaf(acc[ri][r], SCALE_LOG2, NEG_SCALE));
                    rsum[ri][r] += (q * 4 + r == l15) ? 0.f : e;
                }
            } else {
                #pragma unroll
                for (int r = 0; r < 4; ++r)
                    rsum[ri][r] += __builtin_amdgcn_exp2f(
                        __builtin_fmaf(acc[ri][r], SCALE_LOG2, NEG_SCALE));
            }
        }
    }

    // quad-reduce (cols) then one atomic per row per wave
    #pragma unroll
    for (int ri = 0; ri < 4; ++ri)
        #pragma unroll
        for (int r = 0; r < 4; ++r) {
            float s = rsum[ri][r];
            s += __shfl_xor(s, 1);
            s += __shfl_xor(s, 2);
            s += __shfl_xor(s, 4);
            s += __shfl_xor(s, 8);
            if (l15 == 0)
                atomicAdd(&sumexp[rowBase + ri * 16 + q * 4 + r], s);
        }

    // -------- last block computes mean NLL (device-scope handoff) ---------
    __threadfence();
    if (tid == 0) {
        unsigned int prev = __hip_atomic_fetch_add(counter, 1u, __ATOMIC_ACQ_REL,
                                                   __HIP_MEMORY_SCOPE_AGENT);
        isLast = (prev == GRID_SIM - 1);
    }
    __syncthreads();
    if (isLast) {
        float accn = 0.f;
        for (int i = tid; i < N_ROWS; i += 256) {
            const float se = __hip_atomic_load(&sumexp[i], __ATOMIC_RELAXED,
                                               __HIP_MEMORY_SCOPE_AGENT);
            accn += logf(se) - pos[i] * INV_T;
        }
        #pragma unroll
        for (int off = 32; off; off >>= 1) accn += __shfl_xor(accn, off);
        if (lane == 0) redbuf[w] = accn;
        __syncthreads();
        if (tid == 0)
            out[0] = INV_T + (redbuf[0] + redbuf[1] + redbuf[2] + redbuf[3])
                             * (1.f / N_ROWS);
    }
}

extern "C" void kernel_launch(void* const* d_in, const int* in_sizes, int n_in,
                              void* d_out, int out_size, void* d_ws, size_t ws_size,
                              hipStream_t stream) {
    const float* feat = (const float*)d_in[0];
    char* ws = (char*)d_ws;
    char* fbf     = ws;                                              // 4 MB bf16
    float* sumexp = (float*)(ws + 4u*1024u*1024u);                   // 32 KB
    float* pos    = (float*)(ws + 4u*1024u*1024u + 32u*1024u);       // 32 KB
    unsigned int* counter = (unsigned int*)(ws + 4u*1024u*1024u + 64u*1024u);

    k_norm<<<N_ROWS / 4, 256, 0, stream>>>(feat, fbf, sumexp, pos, counter,
                                           (float*)d_out);
    k_sim <<<GRID_SIM,   256, 0, stream>>>(fbf, sumexp, pos, counter,
                                           (float*)d_out);
}